// Round 5
// baseline (322.259 us; speedup 1.0000x reference)
//
#include <hip/hip_runtime.h>
#include <hip/hip_bf16.h>

typedef _Float16 f16;
typedef _Float16 f16x4 __attribute__((ext_vector_type(4)));
typedef _Float16 f16x8 __attribute__((ext_vector_type(8)));
typedef float    f32x4 __attribute__((ext_vector_type(4)));

#define H_DIM 1024
#define S_DIM 1024
#define PLANE (1024*1024)
#define MT 128
#define NT 64
#define KT 32
#define AP (MT*KT)        // one A plane in LDS, f16 elems (4096)
#define ABUF (2*AP)       // one A buffer (2 planes), 8192 f16 = 16 KB
#define XOFF (6*PLANE)    // x_f16 after 2 spans * 3 weight planes

// global -> LDS direct DMA, 16 B/lane; LDS dest = wave-uniform base + lane*16
__device__ __forceinline__ void load_lds16(const f16* g, f16* l) {
    __builtin_amdgcn_global_load_lds(
        (const __attribute__((address_space(1))) void*)g,
        (__attribute__((address_space(3))) void*)l, 16, 0, 0);
}

// Fold weights: Wa = W1+W3, Wb = W2-W3, W4 -> fp16 planes. per span: [Wa, Wb, W4]
__global__ __launch_bounds__(256) void prep_weights(
    const float* __restrict__ Wp1, const float* __restrict__ Wp2,
    const float* __restrict__ Wp3, const float* __restrict__ Wp4,
    const float* __restrict__ Wh1, const float* __restrict__ Wh2,
    const float* __restrict__ Wh3, const float* __restrict__ Wh4,
    f16* __restrict__ ws)
{
    const int span = blockIdx.y;
    const float* W1 = span ? Wh1 : Wp1;
    const float* W2 = span ? Wh2 : Wp2;
    const float* W3 = span ? Wh3 : Wp3;
    const float* W4 = span ? Wh4 : Wp4;
    f16* base = ws + (size_t)span * 3 * PLANE;

    size_t i = ((size_t)blockIdx.x * 256 + threadIdx.x) * 4;
    f32x4 w1 = *(const f32x4*)(W1 + i);
    f32x4 w2 = *(const f32x4*)(W2 + i);
    f32x4 w3 = *(const f32x4*)(W3 + i);
    f32x4 w4 = *(const f32x4*)(W4 + i);

    f16x4 wa, wb, wc;
#pragma unroll
    for (int j = 0; j < 4; ++j) {
        wa[j] = (f16)(w1[j] + w3[j]);
        wb[j] = (f16)(w2[j] - w3[j]);
        wc[j] = (f16)w4[j];
    }
    *(f16x4*)(base + 0*PLANE + i) = wa;
    *(f16x4*)(base + 1*PLANE + i) = wb;
    *(f16x4*)(base + 2*PLANE + i) = wc;
}

// x fp32 -> fp16 (enables global_load_lds DMA for A staging)
__global__ __launch_bounds__(256) void prep_x(const float* __restrict__ x,
                                              f16* __restrict__ xh)
{
    size_t i = ((size_t)blockIdx.x * 256 + threadIdx.x) * 4;
    f32x4 v = *(const f32x4*)(x + i);
    f16x4 h;
#pragma unroll
    for (int j = 0; j < 4; ++j) h[j] = (f16)v[j];
    *(f16x4*)(xh + i) = h;
}

// One pipeline step. BU = B fragments for this kstep, BF = filled for next.
// NOTE: macro-local is `kv` — must NOT shadow the caller's loop variable
// (Round-4 bug: `const int ks = (ks);` self-init UB).
// vmcnt(10) = A(kv+1)[4] + B(kv+1)[6] stay in flight; A(kv)/B(kv) drained.
#define K_STEP(ks_, BU, BF)                                                    \
  {                                                                            \
    const int kv = (ks_);                                                      \
    if (kv < 31) {                                                             \
      _Pragma("unroll")                                                        \
      for (int j = 0; j < 6; ++j) { BF[j] = *(const f16x8*)bp[j]; bp[j] += KT; } \
    }                                                                          \
    if (kv < 31) __asm__ volatile("s_waitcnt vmcnt(10)" ::: "memory");         \
    else         __asm__ volatile("s_waitcnt vmcnt(0)"  ::: "memory");         \
    __builtin_amdgcn_s_barrier();                                              \
    if (kv < 30) {                                                             \
      f16* dst = &A_all[((kv + 2) & 3) * ABUF];                                \
      _Pragma("unroll")                                                        \
      for (int j = 0; j < 4; ++j) { load_lds16(ap[j], dst + adst[j]); ap[j] += KT; } \
    }                                                                          \
    const f16* Ab = &A_all[(kv & 3) * ABUF];                                   \
    f16x8 afr0[4], afr1[4];                                                    \
    _Pragma("unroll")                                                          \
    for (int mf = 0; mf < 4; ++mf) {                                           \
      int r = (wm + mf * 16 + lrow) * KT + lq * 8;                             \
      afr0[mf] = *(const f16x8*)&Ab[r];                                        \
      afr1[mf] = *(const f16x8*)&Ab[AP + r];                                   \
    }                                                                          \
    _Pragma("unroll")                                                          \
    for (int mf = 0; mf < 4; ++mf)                                             \
      _Pragma("unroll")                                                        \
      for (int nf = 0; nf < 2; ++nf) {                                         \
        accL[mf][nf] = __builtin_amdgcn_mfma_f32_16x16x32_f16(afr0[mf], BU[0*2+nf], accL[mf][nf], 0,0,0); \
        accL[mf][nf] = __builtin_amdgcn_mfma_f32_16x16x32_f16(afr1[mf], BU[1*2+nf], accL[mf][nf], 0,0,0); \
        accP[mf][nf] = __builtin_amdgcn_mfma_f32_16x16x32_f16(afr0[mf], BU[2*2+nf], accP[mf][nf], 0,0,0); \
        accQ[mf][nf] = __builtin_amdgcn_mfma_f32_16x16x32_f16(afr1[mf], BU[2*2+nf], accQ[mf][nf], 0,0,0); \
      }                                                                        \
  }

// Fused gather + 4-plane fp16 GEMM + bias/product/tanh epilogue.
// A: LDS, 4 bufs, distance-2 DMA, raw barriers (never vmcnt(0) mid-loop).
// B: global->VGPR, register double-buffered, distance-1 (L2-resident).
// Grid: (32 m-tiles, 16 n-tiles, 2 spans). Block: 256 (4 waves, 2x2 of 64x32).
__global__ __launch_bounds__(256) void span_gemm(
    const f16* __restrict__ xh,
    const int* __restrict__ idxP, const int* __restrict__ idxH,
    const f16* __restrict__ wpl,
    const float* __restrict__ bp1, const float* __restrict__ bp2, const float* __restrict__ bp4,
    const float* __restrict__ bh1, const float* __restrict__ bh2, const float* __restrict__ bh4,
    float* __restrict__ out)
{
    const int t     = threadIdx.x;
    const int mtile = blockIdx.x;
    const int ntile = blockIdx.y;
    const int span  = blockIdx.z;

    const int* idx   = span ? idxH : idxP;
    const f16* wbase = wpl + (size_t)span * 3 * PLANE;
    const float* b1 = span ? bh1 : bp1;
    const float* b2 = span ? bh2 : bp2;
    const float* b4 = span ? bh4 : bp4;
    float* obase = out + (size_t)span * 4096 * H_DIM;

    __shared__ __align__(16) f16 A_all[4 * ABUF];   // 64 KB exactly

    // rowoff aliased onto buf0 (consumed into registers before first DMA lands)
    int* rowoff = (int*)A_all;
    {
        int side = t >> 7, m = t & 127;
        int bk = mtile * MT + m;
        int b  = bk >> 8, kk = bk & 255;
        rowoff[side * 128 + m] = (b * S_DIM + idx[b * 512 + side * 256 + kk]) * H_DIM;
    }
    __syncthreads();

    const int wid  = t >> 6;
    const int lane = t & 63;
    const int wm   = (wid & 1) * 64;
    const int wn   = (wid >> 1) * 32;
    const int lrow = lane & 15;
    const int lq   = lane >> 4;

    // A DMA tasks: 4 ops/wave, each 16 rows x 64 B (contiguous 1 KB block)
    const f16* ap[4]; int adst[4];
#pragma unroll
    for (int j = 0; j < 4; ++j) {
        int o = wid * 4 + j;
        int p = o >> 3, g = o & 7;
        int r = g * 16 + (lane >> 2);
        ap[j]   = xh + rowoff[p * 128 + r] + (lane & 3) * 8;
        adst[j] = p * AP + g * 16 * KT;
    }
    __syncthreads();   // all rowoff reads done before DMA overwrites buf0

    // B fragment pointers: j = p*2+nf
    const f16* bp[6];
#pragma unroll
    for (int j = 0; j < 6; ++j) {
        int p = j >> 1, nf = j & 1;
        int row = ntile * NT + wn + nf * 16 + lrow;
        bp[j] = wbase + (size_t)p * PLANE + (size_t)row * H_DIM + lq * 8;
    }

    f32x4 accL[4][2], accP[4][2], accQ[4][2];
    {
        f32x4 z = {0.f, 0.f, 0.f, 0.f};
#pragma unroll
        for (int mf = 0; mf < 4; ++mf)
#pragma unroll
            for (int nf = 0; nf < 2; ++nf) { accL[mf][nf] = z; accP[mf][nf] = z; accQ[mf][nf] = z; }
    }

    f16x8 bfr0[6], bfr1[6];
    // prologue issue order matters for vmcnt math: A(0)[4], B(0)[6], A(1)[4]
#pragma unroll
    for (int j = 0; j < 4; ++j) { load_lds16(ap[j], &A_all[0 * ABUF + adst[j]]); ap[j] += KT; }
#pragma unroll
    for (int j = 0; j < 6; ++j) { bfr0[j] = *(const f16x8*)bp[j]; bp[j] += KT; }
#pragma unroll
    for (int j = 0; j < 4; ++j) { load_lds16(ap[j], &A_all[1 * ABUF + adst[j]]); ap[j] += KT; }

    for (int ks = 0; ks < 32; ks += 2) {
        K_STEP(ks,     bfr0, bfr1);
        K_STEP(ks + 1, bfr1, bfr0);
    }

    // epilogue: span = L + b1 + b2 + (P+b4)*(Q+b4); out = tanh(span)
    // C/D layout (m89-verified): col = lane&15, row = (lane>>4)*4 + i
#pragma unroll
    for (int mf = 0; mf < 4; ++mf)
#pragma unroll
        for (int nf = 0; nf < 2; ++nf) {
            int col = ntile * NT + wn + nf * 16 + lrow;
            float bb12 = b1[col] + b2[col];
            float bb4  = b4[col];
            int row0 = mtile * MT + wm + mf * 16 + lq * 4;
#pragma unroll
            for (int i = 0; i < 4; ++i) {
                float v = accL[mf][nf][i] + bb12
                        + (accP[mf][nf][i] + bb4) * (accQ[mf][nf][i] + bb4);
                obase[(size_t)(row0 + i) * H_DIM + col] = tanhf(v);
            }
        }
}

extern "C" void kernel_launch(void* const* d_in, const int* in_sizes, int n_in,
                              void* d_out, int out_size, void* d_ws, size_t ws_size,
                              hipStream_t stream) {
    (void)in_sizes; (void)n_in; (void)out_size; (void)ws_size;
    const float* x    = (const float*)d_in[0];
    const int*   idxP = (const int*)d_in[1];
    const int*   idxH = (const int*)d_in[2];
    const float* Wp1 = (const float*)d_in[3];  const float* bp1 = (const float*)d_in[4];
    const float* Wp2 = (const float*)d_in[5];  const float* bp2 = (const float*)d_in[6];
    const float* Wp3 = (const float*)d_in[7];
    const float* Wp4 = (const float*)d_in[9];  const float* bp4 = (const float*)d_in[10];
    const float* Wh1 = (const float*)d_in[11]; const float* bh1 = (const float*)d_in[12];
    const float* Wh2 = (const float*)d_in[13]; const float* bh2 = (const float*)d_in[14];
    const float* Wh3 = (const float*)d_in[15];
    const float* Wh4 = (const float*)d_in[17]; const float* bh4 = (const float*)d_in[18];
    float* out = (float*)d_out;
    f16*   ws  = (f16*)d_ws;   // weights 12 MB + x_f16 32 MB = 44 MB

    prep_weights<<<dim3(1024, 2), 256, 0, stream>>>(Wp1, Wp2, Wp3, Wp4,
                                                    Wh1, Wh2, Wh3, Wh4, ws);
    prep_x<<<16384, 256, 0, stream>>>(x, ws + XOFF);
    span_gemm<<<dim3(32, 16, 2), 256, 0, stream>>>(ws + XOFF, idxP, idxH, ws,
                                                   bp1, bp2, bp4, bh1, bh2, bh4, out);
}

// Round 6
// 320.004 us; speedup vs baseline: 1.0070x; 1.0070x over previous
//
#include <hip/hip_runtime.h>
#include <hip/hip_bf16.h>

typedef _Float16 f16;
typedef _Float16 f16x4 __attribute__((ext_vector_type(4)));
typedef _Float16 f16x8 __attribute__((ext_vector_type(8)));
typedef float    f32x4 __attribute__((ext_vector_type(4)));

#define H_DIM 1024
#define S_DIM 1024
#define PLANE (1024*1024)
#define MT 128
#define NT 64
#define KT 32
#define AP (MT*KT)        // one A plane in LDS, f16 elems (4096)
#define ABUF (2*AP)       // one A buffer (2 planes), 8192 f16 = 16 KB
#define NBUF 3            // 3 buffers: 48 KB total -> 2 blocks/CU (64 KB gave 1)
#define XOFF (6*PLANE)    // x_f16 after 2 spans * 3 weight planes

// global -> LDS direct DMA, 16 B/lane; LDS dest = wave-uniform base + lane*16
__device__ __forceinline__ void load_lds16(const f16* g, f16* l) {
    __builtin_amdgcn_global_load_lds(
        (const __attribute__((address_space(1))) void*)g,
        (__attribute__((address_space(3))) void*)l, 16, 0, 0);
}

// Fold weights: Wa = W1+W3, Wb = W2-W3, W4 -> fp16 planes. per span: [Wa, Wb, W4]
__global__ __launch_bounds__(256) void prep_weights(
    const float* __restrict__ Wp1, const float* __restrict__ Wp2,
    const float* __restrict__ Wp3, const float* __restrict__ Wp4,
    const float* __restrict__ Wh1, const float* __restrict__ Wh2,
    const float* __restrict__ Wh3, const float* __restrict__ Wh4,
    f16* __restrict__ ws)
{
    const int span = blockIdx.y;
    const float* W1 = span ? Wh1 : Wp1;
    const float* W2 = span ? Wh2 : Wp2;
    const float* W3 = span ? Wh3 : Wp3;
    const float* W4 = span ? Wh4 : Wp4;
    f16* base = ws + (size_t)span * 3 * PLANE;

    size_t i = ((size_t)blockIdx.x * 256 + threadIdx.x) * 4;
    f32x4 w1 = *(const f32x4*)(W1 + i);
    f32x4 w2 = *(const f32x4*)(W2 + i);
    f32x4 w3 = *(const f32x4*)(W3 + i);
    f32x4 w4 = *(const f32x4*)(W4 + i);

    f16x4 wa, wb, wc;
#pragma unroll
    for (int j = 0; j < 4; ++j) {
        wa[j] = (f16)(w1[j] + w3[j]);
        wb[j] = (f16)(w2[j] - w3[j]);
        wc[j] = (f16)w4[j];
    }
    *(f16x4*)(base + 0*PLANE + i) = wa;
    *(f16x4*)(base + 1*PLANE + i) = wb;
    *(f16x4*)(base + 2*PLANE + i) = wc;
}

// x fp32 -> fp16 (enables global_load_lds DMA for A staging)
__global__ __launch_bounds__(256) void prep_x(const float* __restrict__ x,
                                              f16* __restrict__ xh)
{
    size_t i = ((size_t)blockIdx.x * 256 + threadIdx.x) * 4;
    f32x4 v = *(const f32x4*)(x + i);
    f16x4 h;
#pragma unroll
    for (int j = 0; j < 4; ++j) h[j] = (f16)v[j];
    *(f16x4*)(xh + i) = h;
}

// One pipeline step. BU = B frags consumed now, BF = filled for next step.
// FILLB: load B(k+1); FILLA: DMA A(k+2); WCNT: vmcnt kept in flight at the wait
//   (10 = A(k+1)[4]+B(k+1)[6] mid-loop; 0 at the last step).
// rb/wb: rotating LDS offsets (read buf k, write buf k+2), wave-uniform scalars.
// Macro-local names must not shadow caller vars (Round-4 self-init bug).
#define K_STEP(FILLB, FILLA, WCNT, BU, BF)                                     \
  {                                                                            \
    if (FILLB) {                                                               \
      _Pragma("unroll")                                                        \
      for (int j = 0; j < 6; ++j) { BF[j] = *(const f16x8*)bp[j]; bp[j] += KT; } \
    }                                                                          \
    __asm__ volatile("s_waitcnt vmcnt(" #WCNT ")" ::: "memory");               \
    __builtin_amdgcn_s_barrier();                                              \
    if (FILLA) {                                                               \
      f16* dst = &A_all[wb];                                                   \
      _Pragma("unroll")                                                        \
      for (int j = 0; j < 4; ++j) { load_lds16(ap[j], dst + adst[j]); ap[j] += KT; } \
    }                                                                          \
    const f16* Ab = &A_all[rb];                                                \
    f16x8 afr0[4], afr1[4];                                                    \
    _Pragma("unroll")                                                          \
    for (int mf = 0; mf < 4; ++mf) {                                           \
      int r = (wm + mf * 16 + lrow) * KT + lq * 8;                             \
      afr0[mf] = *(const f16x8*)&Ab[r];                                        \
      afr1[mf] = *(const f16x8*)&Ab[AP + r];                                   \
    }                                                                          \
    _Pragma("unroll")                                                          \
    for (int mf = 0; mf < 4; ++mf)                                             \
      _Pragma("unroll")                                                        \
      for (int nf = 0; nf < 2; ++nf) {                                         \
        accL[mf][nf] = __builtin_amdgcn_mfma_f32_16x16x32_f16(afr0[mf], BU[0*2+nf], accL[mf][nf], 0,0,0); \
        accL[mf][nf] = __builtin_amdgcn_mfma_f32_16x16x32_f16(afr1[mf], BU[1*2+nf], accL[mf][nf], 0,0,0); \
        accP[mf][nf] = __builtin_amdgcn_mfma_f32_16x16x32_f16(afr0[mf], BU[2*2+nf], accP[mf][nf], 0,0,0); \
        accQ[mf][nf] = __builtin_amdgcn_mfma_f32_16x16x32_f16(afr1[mf], BU[2*2+nf], accQ[mf][nf], 0,0,0); \
      }                                                                        \
    rb = (rb == 2 * ABUF) ? 0 : rb + ABUF;                                     \
    wb = (wb == 2 * ABUF) ? 0 : wb + ABUF;                                     \
  }

// Fused gather + 4-plane fp16 GEMM + bias/product/tanh epilogue.
// A: LDS, 3 bufs (48 KB), distance-2 DMA, raw barriers, never vmcnt(0) mid-loop.
// B: global->VGPR, register double-buffered, distance-1 (L2-resident).
// Grid: (32 m-tiles, 16 n-tiles, 2 spans). Block: 256 (4 waves, 2x2 of 64x32).
__global__ __launch_bounds__(256) void span_gemm(
    const f16* __restrict__ xh,
    const int* __restrict__ idxP, const int* __restrict__ idxH,
    const f16* __restrict__ wpl,
    const float* __restrict__ bp1, const float* __restrict__ bp2, const float* __restrict__ bp4,
    const float* __restrict__ bh1, const float* __restrict__ bh2, const float* __restrict__ bh4,
    float* __restrict__ out)
{
    const int t     = threadIdx.x;
    const int mtile = blockIdx.x;
    const int ntile = blockIdx.y;
    const int span  = blockIdx.z;

    const int* idx   = span ? idxH : idxP;
    const f16* wbase = wpl + (size_t)span * 3 * PLANE;
    const float* b1 = span ? bh1 : bp1;
    const float* b2 = span ? bh2 : bp2;
    const float* b4 = span ? bh4 : bp4;
    float* obase = out + (size_t)span * 4096 * H_DIM;

    __shared__ __align__(16) f16 A_all[NBUF * ABUF];   // 48 KB

    // rowoff aliased onto buf0 (consumed into registers before first DMA lands)
    int* rowoff = (int*)A_all;
    {
        int side = t >> 7, m = t & 127;
        int bk = mtile * MT + m;
        int b  = bk >> 8, kk = bk & 255;
        rowoff[side * 128 + m] = (b * S_DIM + idx[b * 512 + side * 256 + kk]) * H_DIM;
    }
    __syncthreads();

    const int wid  = t >> 6;
    const int lane = t & 63;
    const int wm   = (wid & 1) * 64;
    const int wn   = (wid >> 1) * 32;
    const int lrow = lane & 15;
    const int lq   = lane >> 4;

    // A DMA tasks: 4 ops/wave, each 16 rows x 64 B (contiguous 1 KB block)
    const f16* ap[4]; int adst[4];
#pragma unroll
    for (int j = 0; j < 4; ++j) {
        int o = wid * 4 + j;
        int p = o >> 3, g = o & 7;
        int r = g * 16 + (lane >> 2);
        ap[j]   = xh + rowoff[p * 128 + r] + (lane & 3) * 8;
        adst[j] = p * AP + g * 16 * KT;
    }
    __syncthreads();   // all rowoff reads done before DMA overwrites buf0

    // B fragment pointers: j = p*2+nf
    const f16* bp[6];
#pragma unroll
    for (int j = 0; j < 6; ++j) {
        int p = j >> 1, nf = j & 1;
        int row = ntile * NT + wn + nf * 16 + lrow;
        bp[j] = wbase + (size_t)p * PLANE + (size_t)row * H_DIM + lq * 8;
    }

    f32x4 accL[4][2], accP[4][2], accQ[4][2];
    {
        f32x4 z = {0.f, 0.f, 0.f, 0.f};
#pragma unroll
        for (int mf = 0; mf < 4; ++mf)
#pragma unroll
            for (int nf = 0; nf < 2; ++nf) { accL[mf][nf] = z; accP[mf][nf] = z; accQ[mf][nf] = z; }
    }

    f16x8 bfr0[6], bfr1[6];
    // prologue issue order matters for vmcnt math: A(0)[4], B(0)[6], A(1)[4]
#pragma unroll
    for (int j = 0; j < 4; ++j) { load_lds16(ap[j], &A_all[0 * ABUF + adst[j]]); ap[j] += KT; }
#pragma unroll
    for (int j = 0; j < 6; ++j) { bfr0[j] = *(const f16x8*)bp[j]; bp[j] += KT; }
#pragma unroll
    for (int j = 0; j < 4; ++j) { load_lds16(ap[j], &A_all[1 * ABUF + adst[j]]); ap[j] += KT; }

    int rb = 0;           // read-buffer LDS offset (buf k)
    int wb = 2 * ABUF;    // write-buffer LDS offset (buf k+2)

    for (int ks = 0; ks < 30; ks += 2) {
        K_STEP(1, 1, 10, bfr0, bfr1);
        K_STEP(1, 1, 10, bfr1, bfr0);
    }
    K_STEP(1, 0, 10, bfr0, bfr1);   // ks=30: fill B(31), no A(32)
    K_STEP(0, 0, 0,  bfr1, bfr0);   // ks=31: final drain

    // epilogue: span = L + b1 + b2 + (P+b4)*(Q+b4); out = tanh(span)
    // C/D layout (m89-verified): col = lane&15, row = (lane>>4)*4 + i
#pragma unroll
    for (int mf = 0; mf < 4; ++mf)
#pragma unroll
        for (int nf = 0; nf < 2; ++nf) {
            int col = ntile * NT + wn + nf * 16 + lrow;
            float bb12 = b1[col] + b2[col];
            float bb4  = b4[col];
            int row0 = mtile * MT + wm + mf * 16 + lq * 4;
#pragma unroll
            for (int i = 0; i < 4; ++i) {
                float v = accL[mf][nf][i] + bb12
                        + (accP[mf][nf][i] + bb4) * (accQ[mf][nf][i] + bb4);
                obase[(size_t)(row0 + i) * H_DIM + col] = tanhf(v);
            }
        }
}

extern "C" void kernel_launch(void* const* d_in, const int* in_sizes, int n_in,
                              void* d_out, int out_size, void* d_ws, size_t ws_size,
                              hipStream_t stream) {
    (void)in_sizes; (void)n_in; (void)out_size; (void)ws_size;
    const float* x    = (const float*)d_in[0];
    const int*   idxP = (const int*)d_in[1];
    const int*   idxH = (const int*)d_in[2];
    const float* Wp1 = (const float*)d_in[3];  const float* bp1 = (const float*)d_in[4];
    const float* Wp2 = (const float*)d_in[5];  const float* bp2 = (const float*)d_in[6];
    const float* Wp3 = (const float*)d_in[7];
    const float* Wp4 = (const float*)d_in[9];  const float* bp4 = (const float*)d_in[10];
    const float* Wh1 = (const float*)d_in[11]; const float* bh1 = (const float*)d_in[12];
    const float* Wh2 = (const float*)d_in[13]; const float* bh2 = (const float*)d_in[14];
    const float* Wh3 = (const float*)d_in[15];
    const float* Wh4 = (const float*)d_in[17]; const float* bh4 = (const float*)d_in[18];
    float* out = (float*)d_out;
    f16*   ws  = (f16*)d_ws;   // weights 12 MB + x_f16 32 MB = 44 MB

    prep_weights<<<dim3(1024, 2), 256, 0, stream>>>(Wp1, Wp2, Wp3, Wp4,
                                                    Wh1, Wh2, Wh3, Wh4, ws);
    prep_x<<<16384, 256, 0, stream>>>(x, ws + XOFF);
    span_gemm<<<dim3(32, 16, 2), 256, 0, stream>>>(ws + XOFF, idxP, idxH, ws,
                                                   bp1, bp2, bp4, bh1, bh2, bh4, out);
}

// Round 7
// 244.194 us; speedup vs baseline: 1.3197x; 1.3105x over previous
//
#include <hip/hip_runtime.h>
#include <hip/hip_bf16.h>

typedef _Float16 f16;
typedef _Float16 f16x4 __attribute__((ext_vector_type(4)));
typedef _Float16 f16x8 __attribute__((ext_vector_type(8)));
typedef float    f32x4 __attribute__((ext_vector_type(4)));

#define H_DIM 1024
#define S_DIM 1024
#define PLANE (1024*1024)
#define MT 128
#define NT 64
#define KT 32
#define AP (MT*KT)        // one A plane in LDS, f16 elems (4096)
#define ABUF (2*AP)       // one A buffer (2 planes), 8192 f16 = 16 KB
#define XOFF (6*PLANE)    // x_f16 after 2 spans * 3 weight planes

// global -> LDS direct DMA, 16 B/lane; LDS dest = wave-uniform base + lane*16
__device__ __forceinline__ void load_lds16(const f16* g, f16* l) {
    __builtin_amdgcn_global_load_lds(
        (const __attribute__((address_space(1))) void*)g,
        (__attribute__((address_space(3))) void*)l, 16, 0, 0);
}

// Merged prep (one launch): blocks [0,16384) convert x fp32->fp16;
// blocks [16384,18432) fold weights Wa=W1+W3, Wb=W2-W3, W4 -> fp16 planes.
__global__ __launch_bounds__(256) void prep_all(
    const float* __restrict__ x,
    const float* __restrict__ Wp1, const float* __restrict__ Wp2,
    const float* __restrict__ Wp3, const float* __restrict__ Wp4,
    const float* __restrict__ Wh1, const float* __restrict__ Wh2,
    const float* __restrict__ Wh3, const float* __restrict__ Wh4,
    f16* __restrict__ ws)
{
    int bx = blockIdx.x;
    if (bx < 16384) {
        size_t i = ((size_t)bx * 256 + threadIdx.x) * 4;
        f32x4 v = *(const f32x4*)(x + i);
        f16x4 h;
#pragma unroll
        for (int j = 0; j < 4; ++j) h[j] = (f16)v[j];
        *(f16x4*)(ws + XOFF + i) = h;
        return;
    }
    bx -= 16384;
    const int span = bx >> 10;
    const int blk  = bx & 1023;
    const float* W1 = span ? Wh1 : Wp1;
    const float* W2 = span ? Wh2 : Wp2;
    const float* W3 = span ? Wh3 : Wp3;
    const float* W4 = span ? Wh4 : Wp4;
    f16* base = ws + (size_t)span * 3 * PLANE;

    size_t i = ((size_t)blk * 256 + threadIdx.x) * 4;
    f32x4 w1 = *(const f32x4*)(W1 + i);
    f32x4 w2 = *(const f32x4*)(W2 + i);
    f32x4 w3 = *(const f32x4*)(W3 + i);
    f32x4 w4 = *(const f32x4*)(W4 + i);

    f16x4 wa, wb, wc;
#pragma unroll
    for (int j = 0; j < 4; ++j) {
        wa[j] = (f16)(w1[j] + w3[j]);
        wb[j] = (f16)(w2[j] - w3[j]);
        wc[j] = (f16)w4[j];
    }
    *(f16x4*)(base + 0*PLANE + i) = wa;
    *(f16x4*)(base + 1*PLANE + i) = wb;
    *(f16x4*)(base + 2*PLANE + i) = wc;
}

// One pipeline step.
//   FB: DMA B(k+1) into the (single) B buffer; FA: DMA A(k+2) into A buf wbA.
//   WCNT: vmcnt kept in flight at the step-end wait (4 = A(k+2); 0 at tail).
//   FIN: final step — no barriers/DMA.
// Two-barrier step: frag reads -> lgkmcnt(0)+bar1 (reads retired, B buf safe
// to overwrite) -> DMA issues (untracked, vmcnt only) -> MFMAs -> vmcnt(WCNT)
// +bar2 (next kstep's data landed; fresh A(k+2) prefetch STAYS in flight).
// No register-destination global loads in the loop => the compiler has no
// vmcnt dependencies to conservatively re-wait on (Round-5/6 failure mode).
#define K_STEP(FB, FA, WCNT, FIN)                                              \
  {                                                                            \
    f16x8 afr0[4], afr1[4], bfrg[6];                                           \
    const f16* Ab = &A_all[rbA];                                               \
    _Pragma("unroll")                                                          \
    for (int mf = 0; mf < 4; ++mf) {                                           \
      int r = (wm + mf * 16 + lrow) * KT + lq * 8;                             \
      afr0[mf] = *(const f16x8*)&Ab[r];                                        \
      afr1[mf] = *(const f16x8*)&Ab[AP + r];                                   \
    }                                                                          \
    _Pragma("unroll")                                                          \
    for (int j = 0; j < 6; ++j) {                                              \
      int p = j >> 1, nf = j & 1;                                              \
      bfrg[j] = *(const f16x8*)&B_lds[p * 2048 + (wn + nf * 16 + lrow) * KT + lq * 8]; \
    }                                                                          \
    if (!(FIN)) {                                                              \
      __asm__ volatile("s_waitcnt lgkmcnt(0)" ::: "memory");                   \
      __builtin_amdgcn_s_barrier();                                            \
      if (FB) {                                                                \
        _Pragma("unroll")                                                      \
        for (int j = 0; j < 3; ++j) { load_lds16(bq[j], &B_lds[bdst[j]]); bq[j] += KT; } \
      }                                                                        \
      if (FA) {                                                                \
        f16* dst = &A_all[wbA];                                                \
        _Pragma("unroll")                                                      \
        for (int j = 0; j < 4; ++j) { load_lds16(ap[j], dst + adst[j]); ap[j] += KT; } \
      }                                                                        \
    }                                                                          \
    _Pragma("unroll")                                                          \
    for (int mf = 0; mf < 4; ++mf)                                             \
      _Pragma("unroll")                                                        \
      for (int nf = 0; nf < 2; ++nf) {                                         \
        accL[mf][nf] = __builtin_amdgcn_mfma_f32_16x16x32_f16(afr0[mf], bfrg[0*2+nf], accL[mf][nf], 0,0,0); \
        accL[mf][nf] = __builtin_amdgcn_mfma_f32_16x16x32_f16(afr1[mf], bfrg[1*2+nf], accL[mf][nf], 0,0,0); \
        accP[mf][nf] = __builtin_amdgcn_mfma_f32_16x16x32_f16(afr0[mf], bfrg[2*2+nf], accP[mf][nf], 0,0,0); \
        accQ[mf][nf] = __builtin_amdgcn_mfma_f32_16x16x32_f16(afr1[mf], bfrg[2*2+nf], accQ[mf][nf], 0,0,0); \
      }                                                                        \
    if (!(FIN)) {                                                              \
      __asm__ volatile("s_waitcnt vmcnt(" #WCNT ")" ::: "memory");             \
      __builtin_amdgcn_s_barrier();                                            \
      rbA = (rbA == 2 * ABUF) ? 0 : rbA + ABUF;                                \
      wbA = (wbA == 2 * ABUF) ? 0 : wbA + ABUF;                                \
    }                                                                          \
  }

// Fused gather + 4-plane fp16 GEMM + bias/product/tanh epilogue.
// A: LDS 3 bufs (48 KB), distance-2 DMA. B: LDS 1 buf (12 KB), in-place
// refresh guarded by barrier1. Total 60 KB < 64 KB cap -> 2 blocks/CU.
// Grid: (32 m-tiles, 16 n-tiles, 2 spans). Block: 256 (4 waves, 2x2 of 64x32).
__global__ __launch_bounds__(256) void span_gemm(
    const f16* __restrict__ xh,
    const int* __restrict__ idxP, const int* __restrict__ idxH,
    const f16* __restrict__ wpl,
    const float* __restrict__ bp1, const float* __restrict__ bp2, const float* __restrict__ bp4,
    const float* __restrict__ bh1, const float* __restrict__ bh2, const float* __restrict__ bh4,
    float* __restrict__ out)
{
    const int t     = threadIdx.x;
    const int mtile = blockIdx.x;
    const int ntile = blockIdx.y;
    const int span  = blockIdx.z;

    const int* idx   = span ? idxH : idxP;
    const f16* wbase = wpl + (size_t)span * 3 * PLANE;
    const float* b1 = span ? bh1 : bp1;
    const float* b2 = span ? bh2 : bp2;
    const float* b4 = span ? bh4 : bp4;
    float* obase = out + (size_t)span * 4096 * H_DIM;

    __shared__ __align__(16) f16 A_all[3 * ABUF];   // 48 KB
    __shared__ __align__(16) f16 B_lds[3 * NT * KT]; // 12 KB, single buffer

    // rowoff aliased onto A buf0 (consumed into registers before first DMA)
    int* rowoff = (int*)A_all;
    {
        int side = t >> 7, m = t & 127;
        int bk = mtile * MT + m;
        int b  = bk >> 8, kk = bk & 255;
        rowoff[side * 128 + m] = (b * S_DIM + idx[b * 512 + side * 256 + kk]) * H_DIM;
    }
    __syncthreads();

    const int wid  = t >> 6;
    const int lane = t & 63;
    const int wm   = (wid & 1) * 64;
    const int wn   = (wid >> 1) * 32;
    const int lrow = lane & 15;
    const int lq   = lane >> 4;

    // A DMA tasks: 4 ops/wave, each 16 rows x 64 B (contiguous 1 KB block)
    const f16* ap[4]; int adst[4];
#pragma unroll
    for (int j = 0; j < 4; ++j) {
        int o = wid * 4 + j;
        int p = o >> 3, g = o & 7;
        int r = g * 16 + (lane >> 2);
        ap[j]   = xh + rowoff[p * 128 + r] + (lane & 3) * 8;
        adst[j] = p * AP + g * 16 * KT;
    }
    __syncthreads();   // all rowoff reads done before DMA overwrites buf0

    // B DMA tasks: 3 ops/wave (12 total: 3 planes x 4 row-groups of 16)
    const f16* bq[3]; int bdst[3];
#pragma unroll
    for (int j = 0; j < 3; ++j) {
        int o = wid * 3 + j;
        int p = o >> 2, g = o & 3;
        int grow = ntile * NT + g * 16 + (lane >> 2);
        bq[j]   = wbase + (size_t)p * PLANE + (size_t)grow * H_DIM + (lane & 3) * 8;
        bdst[j] = p * 2048 + g * 16 * KT;
    }

    f32x4 accL[4][2], accP[4][2], accQ[4][2];
    {
        f32x4 z = {0.f, 0.f, 0.f, 0.f};
#pragma unroll
        for (int mf = 0; mf < 4; ++mf)
#pragma unroll
            for (int nf = 0; nf < 2; ++nf) { accL[mf][nf] = z; accP[mf][nf] = z; accQ[mf][nf] = z; }
    }

    // prologue: A(0), B(0), A(1); drain A(0)+B(0), keep A(1) in flight
#pragma unroll
    for (int j = 0; j < 4; ++j) { load_lds16(ap[j], &A_all[0 * ABUF + adst[j]]); ap[j] += KT; }
#pragma unroll
    for (int j = 0; j < 3; ++j) { load_lds16(bq[j], &B_lds[bdst[j]]); bq[j] += KT; }
#pragma unroll
    for (int j = 0; j < 4; ++j) { load_lds16(ap[j], &A_all[1 * ABUF + adst[j]]); ap[j] += KT; }
    __asm__ volatile("s_waitcnt vmcnt(4)" ::: "memory");
    __builtin_amdgcn_s_barrier();

    int rbA = 0;          // A read buffer (kstep k)
    int wbA = 2 * ABUF;   // A write buffer (kstep k+2)

    for (int ks = 0; ks < 30; ++ks) {
        K_STEP(1, 1, 4, 0);
    }
    K_STEP(1, 0, 0, 0);   // ks=30: fill B(31), no A(32), drain all
    K_STEP(0, 0, 0, 1);   // ks=31: compute only

    // epilogue: span = L + b1 + b2 + (P+b4)*(Q+b4); out = tanh(span)
    // C/D layout (m89-verified): col = lane&15, row = (lane>>4)*4 + i
#pragma unroll
    for (int mf = 0; mf < 4; ++mf)
#pragma unroll
        for (int nf = 0; nf < 2; ++nf) {
            int col = ntile * NT + wn + nf * 16 + lrow;
            float bb12 = b1[col] + b2[col];
            float bb4  = b4[col];
            int row0 = mtile * MT + wm + mf * 16 + lq * 4;
#pragma unroll
            for (int i = 0; i < 4; ++i) {
                float v = accL[mf][nf][i] + bb12
                        + (accP[mf][nf][i] + bb4) * (accQ[mf][nf][i] + bb4);
                obase[(size_t)(row0 + i) * H_DIM + col] = tanhf(v);
            }
        }
}

extern "C" void kernel_launch(void* const* d_in, const int* in_sizes, int n_in,
                              void* d_out, int out_size, void* d_ws, size_t ws_size,
                              hipStream_t stream) {
    (void)in_sizes; (void)n_in; (void)out_size; (void)ws_size;
    const float* x    = (const float*)d_in[0];
    const int*   idxP = (const int*)d_in[1];
    const int*   idxH = (const int*)d_in[2];
    const float* Wp1 = (const float*)d_in[3];  const float* bp1 = (const float*)d_in[4];
    const float* Wp2 = (const float*)d_in[5];  const float* bp2 = (const float*)d_in[6];
    const float* Wp3 = (const float*)d_in[7];
    const float* Wp4 = (const float*)d_in[9];  const float* bp4 = (const float*)d_in[10];
    const float* Wh1 = (const float*)d_in[11]; const float* bh1 = (const float*)d_in[12];
    const float* Wh2 = (const float*)d_in[13]; const float* bh2 = (const float*)d_in[14];
    const float* Wh3 = (const float*)d_in[15];
    const float* Wh4 = (const float*)d_in[17]; const float* bh4 = (const float*)d_in[18];
    float* out = (float*)d_out;
    f16*   ws  = (f16*)d_ws;   // weights 12 MB + x_f16 32 MB = 44 MB

    prep_all<<<18432, 256, 0, stream>>>(x, Wp1, Wp2, Wp3, Wp4,
                                        Wh1, Wh2, Wh3, Wh4, ws);
    span_gemm<<<dim3(32, 16, 2), 256, 0, stream>>>(ws + XOFF, idxP, idxH, ws,
                                                   bp1, bp2, bp4, bh1, bh2, bh4, out);
}